// Round 7
// baseline (484.334 us; speedup 1.0000x reference)
//
#include <hip/hip_runtime.h>
#include <hip/hip_bf16.h>
#include <cstdint>
#include <cstddef>

#define IN_DIM 1024
#define OUT_DIM 1024
#define NE 8
#define NTOK 8192
#define MT_TILES 20   // 2560-row capacity per expert (counts ~2048+-42)

typedef __bf16 bf16x8 __attribute__((ext_vector_type(8)));
typedef float f32x4 __attribute__((ext_vector_type(4)));
typedef unsigned short ushort8v __attribute__((ext_vector_type(8)));

// RNE float -> bf16 bits
__device__ __forceinline__ unsigned short f2bf(float f) {
    unsigned u = __float_as_uint(f);
    unsigned r = 0x7fffu + ((u >> 16) & 1u);
    return (unsigned short)((u + r) >> 16);
}

// async global->LDS, 16B per lane. lds must be wave-uniform base; g is per-lane.
__device__ __forceinline__ void async16(void* lds, const void* g) {
    __builtin_amdgcn_global_load_lds(
        (const __attribute__((address_space(1))) unsigned int*)g,
        (__attribute__((address_space(3))) unsigned int*)lds,
        16, 0, 0);
}

// ---------------- weight convert + transpose: [K][N] fp32 -> [N][K] bf16 ----
// R5: pad 69 (transpose-read stride 16x69 = 16 mod 32 -> 2-way bank aliasing,
// free) and 8-threads-per-output-row write phase (contiguous 128B runs).
__global__ __launch_bounds__(256) void convert_transpose_kernel(
    const float* __restrict__ w1, const float* __restrict__ w2,
    unsigned short* __restrict__ w1T, unsigned short* __restrict__ w2T) {
    __shared__ float tile[64][69];
    int z = blockIdx.z; // 0..7 -> w1 experts, 8..15 -> w2 experts
    const float* src = (z < 8) ? (w1 + (size_t)z * IN_DIM * OUT_DIM)
                               : (w2 + (size_t)(z - 8) * OUT_DIM * OUT_DIM);
    unsigned short* dst = (z < 8) ? (w1T + (size_t)z * IN_DIM * OUT_DIM)
                                  : (w2T + (size_t)(z - 8) * OUT_DIM * OUT_DIM);
    int kt = blockIdx.x * 64, nt = blockIdx.y * 64;
    int t = threadIdx.x;
    int r = t >> 2, cq = (t & 3) * 16;
#pragma unroll
    for (int q = 0; q < 4; ++q) {
        float4 v = *(const float4*)(src + (size_t)(kt + r) * 1024 + nt + cq + q * 4);
        tile[r][cq + q * 4 + 0] = v.x;
        tile[r][cq + q * 4 + 1] = v.y;
        tile[r][cq + q * 4 + 2] = v.z;
        tile[r][cq + q * 4 + 3] = v.w;
    }
    __syncthreads();
    int n2 = t >> 3, k8 = (t & 7) * 8;
#pragma unroll
    for (int q = 0; q < 2; ++q) {
        int n = n2 + q * 32;
        ushort8v o;
#pragma unroll
        for (int i = 0; i < 8; ++i) o[i] = f2bf(tile[k8 + i][n]);
        *(ushort8v*)(dst + (size_t)(nt + n) * 1024 + kt + k8) = o;
    }
}

// ---------------- router: logits, top-2, softmax, x->bf16 -------------------
__global__ __launch_bounds__(256) void router_kernel(
    const float* __restrict__ x, const float* __restrict__ rw,
    const float* __restrict__ rb,
    unsigned short* __restrict__ xb,
    float* __restrict__ gating, int* __restrict__ enc,
    float2* __restrict__ gw, int* __restrict__ cnt) {
    __shared__ float srw[NE * IN_DIM]; // transposed: srw[e*1024 + k]
    int t = threadIdx.x;
    if (blockIdx.x == 0 && t < NE) cnt[t] = 0;   // zero counters for bucket
#pragma unroll
    for (int i = 0; i < 4; ++i) {
        int k = t + i * 256;
        float4 a = *(const float4*)(rw + (size_t)k * NE);
        float4 b = *(const float4*)(rw + (size_t)k * NE + 4);
        srw[0 * IN_DIM + k] = a.x; srw[1 * IN_DIM + k] = a.y;
        srw[2 * IN_DIM + k] = a.z; srw[3 * IN_DIM + k] = a.w;
        srw[4 * IN_DIM + k] = b.x; srw[5 * IN_DIM + k] = b.y;
        srw[6 * IN_DIM + k] = b.z; srw[7 * IN_DIM + k] = b.w;
    }
    __syncthreads();
    int wave = t >> 6, lane = t & 63;
    int tok = blockIdx.x * 4 + wave;
    const float* xrow = x + (size_t)tok * IN_DIM;
    unsigned short* xbrow = xb + (size_t)tok * IN_DIM;
    float acc[NE] = {0, 0, 0, 0, 0, 0, 0, 0};
#pragma unroll
    for (int i = 0; i < 4; ++i) {
        int k = i * 256 + lane * 4;
        float4 xv = *(const float4*)(xrow + k);
        ushort4 o;
        o.x = f2bf(xv.x); o.y = f2bf(xv.y); o.z = f2bf(xv.z); o.w = f2bf(xv.w);
        *(ushort4*)(xbrow + k) = o;
#pragma unroll
        for (int e = 0; e < NE; ++e) {
            float4 wv = *(const float4*)(srw + e * IN_DIM + k);
            acc[e] = fmaf(xv.x, wv.x, fmaf(xv.y, wv.y, fmaf(xv.z, wv.z, fmaf(xv.w, wv.w, acc[e]))));
        }
    }
#pragma unroll
    for (int e = 0; e < NE; ++e) {
#pragma unroll
        for (int off = 32; off > 0; off >>= 1) acc[e] += __shfl_xor(acc[e], off);
        acc[e] += rb[e];
    }
    // top-2 (lowest index wins ties, matching lax.top_k)
    int e0 = 0; float v0 = acc[0];
#pragma unroll
    for (int e = 1; e < NE; ++e) if (acc[e] > v0) { v0 = acc[e]; e0 = e; }
    int e1 = -1; float v1 = -3.4e38f;
#pragma unroll
    for (int e = 0; e < NE; ++e) if (e != e0 && acc[e] > v1) { v1 = acc[e]; e1 = e; }
    float tg = __expf(v1 - v0);
    float inv = 1.0f / (1.0f + tg);
    float g0 = inv, g1 = tg * inv;
    if (lane < NE) gating[(size_t)tok * NE + lane] = (lane == e0) ? g0 : ((lane == e1) ? g1 : 0.0f);
    if (lane == 0) {
        enc[tok] = e0 | (e1 << 8);
        gw[tok] = make_float2(g0, g1);
    }
}

// ---------------- bucket: wave-aggregated atomic compaction ------------------
// R7: bidx entry packs tok | (which<<15); slots array removed (combine fused
// into gemm2 epilogue reads the which-bit + gw directly).
__global__ __launch_bounds__(256) void bucket_kernel(
    const int* __restrict__ enc,
    int* __restrict__ bidx, int* __restrict__ cnt) {
    int tok = blockIdx.x * 256 + threadIdx.x;
    int lane = threadIdx.x & 63;
    int v = enc[tok];
    int e0 = v & 0xff, e1 = (v >> 8) & 0xff;
    unsigned long long below = (1ull << lane) - 1ull;
    int p0 = 0, p1 = 0;
#pragma unroll
    for (int e = 0; e < NE; ++e) {
        unsigned long long m0 = __ballot(e0 == e);
        unsigned long long m1 = __ballot(e1 == e);
        int c0 = __popcll(m0), c1 = __popcll(m1);
        int base = 0;
        if (lane == 0 && (c0 + c1)) base = atomicAdd(&cnt[e], c0 + c1);
        base = __shfl(base, 0);
        if (e0 == e) p0 = base + __popcll(m0 & below);
        if (e1 == e) p1 = base + c0 + __popcll(m1 & below);
    }
    bidx[e0 * NTOK + p0] = tok;              // which = 0
    bidx[e1 * NTOK + p1] = tok | 0x8000;     // which = 1
}

// inline 8-entry exclusive prefix of cnt up to e (uniform scalar loads)
__device__ __forceinline__ int prefix_cnt(const int* __restrict__ cnt, int e) {
    int s = 0;
    for (int i = 0; i < NE; ++i) s += (i < e) ? cnt[i] : 0;
    return s;
}

// ---------------- GEMM K-step: ds_read fragments + 16 MFMA ------------------
__device__ __forceinline__ void kstep(const unsigned short* Ab,
                                      const unsigned short* Bb,
                                      f32x4 (&acc)[4][4], int wm, int wn,
                                      int lhalf, int slot) {
    bf16x8 av[4], bv[4];
#pragma unroll
    for (int i = 0; i < 4; ++i)
        av[i] = *(const bf16x8*)(Ab + (wm * 32 + i * 8 + lhalf) * 64 + slot);
#pragma unroll
    for (int j = 0; j < 4; ++j)
        bv[j] = *(const bf16x8*)(Bb + (wn * 32 + j * 8 + lhalf) * 64 + slot);
#pragma unroll
    for (int i = 0; i < 4; ++i)
#pragma unroll
        for (int j = 0; j < 4; ++j)
            acc[i][j] = __builtin_amdgcn_mfma_f32_16x16x32_bf16(av[i], bv[j], acc[i][j], 0, 0, 0);
}

// ---------------- GEMM K-loop (shared by gemm1/gemm2) -----------------------
// R3-verified structure (66/64.5 us): 128x128 tile, BK=32, THREE LDS buffers
// (48 KB -> 3 blocks/CU = 12 waves/CU), depth-2 counted vmcnt(4).
// Plateau ledger (R0-R4): >=12 waves/CU => ~65 us regardless of drain vs
// counted vs LDS traffic; <12 waves/CU regresses. Latency-quantization
// plateau of this tile family; all throughput pipes have >=2x slack.
// LDS layout per buffer: 64 lines x 128B; line L packs 2 rows (32 K-elems
// each) as 8 chunks of 16B, XOR-swizzled: slot = chunk ^ (L&7).
// B-row PERMUTATION (R0): B staged so fragment (j,l15) = output column
// n = wn*64 + 4*l15 + j  -> epilogue j=0..3 are 4 consecutive columns.

// ---------------- GEMM1: H = relu(gather(Xb) @ W1 + b1), bf16 out ----------
__global__ __launch_bounds__(256) void gemm1_kernel(
    const unsigned short* __restrict__ xb, const unsigned short* __restrict__ w1T,
    const float* __restrict__ b1, const int* __restrict__ bidx,
    const int* __restrict__ cnt,
    unsigned short* __restrict__ H) {
    int b = blockIdx.x;
    int e = b & 7;          // XCD pin: all of expert e on XCD e
    int t2 = b >> 3;
    int nt = t2 & 7;
    int mt = t2 >> 3;
    int n_e = cnt[e];
    if (mt * 128 >= n_e) return;
    __shared__ __attribute__((aligned(16))) unsigned short As[3][64 * 64];
    __shared__ __attribute__((aligned(16))) unsigned short Bs[3][64 * 64];
    int t = threadIdx.x, wave = t >> 6, lane = t & 63;
    const int* be = bidx + e * NTOK;
    const unsigned short* agp[2]; const unsigned short* bgp[2];
    int ldsoff[2];
#pragma unroll
    for (int is = 0; is < 2; ++is) {
        int c = is * 256 + t;
        int line = c >> 3;
        int chunkg = (c & 7) ^ (line & 7);
        int sub = chunkg >> 2;
        int growl = 2 * line + sub;                       // A row (unchanged)
        int growlB = (line >> 5) * 64 + (line & 7) * 8 + sub * 4 + ((line >> 3) & 3);
        int gcol = (chunkg & 3) * 8;
        int gra = mt * 128 + growl;
        int grac = gra < n_e ? gra : n_e - 1;
        agp[is] = xb + (size_t)(be[grac] & 0x7fff) * IN_DIM + gcol;
        bgp[is] = w1T + ((size_t)e * OUT_DIM + nt * 128 + growlB) * IN_DIM + gcol;
        ldsoff[is] = (is * 256 + wave * 64) * 8; // elements; lane*16B appended by HW
    }
    int wm = wave & 1, wn = wave >> 1;
    int quad = lane >> 4, l15 = lane & 15;
    int lhalf = l15 >> 1;                       // = line&7 for all frags
    int slot = (((l15 & 1) * 4 + quad) ^ lhalf) * 8; // element offset in line
    f32x4 zero4 = {0.f, 0.f, 0.f, 0.f};
    f32x4 acc[4][4];
#pragma unroll
    for (int i = 0; i < 4; ++i)
#pragma unroll
        for (int j = 0; j < 4; ++j) acc[i][j] = zero4;

    // prologue: stage k-tiles 0..1 into buffers 0..1 (8 loads/wave in flight)
#pragma unroll
    for (int pt = 0; pt < 2; ++pt)
#pragma unroll
        for (int is = 0; is < 2; ++is) {
            async16(&As[pt][ldsoff[is]], agp[is] + pt * 32);
            async16(&Bs[pt][ldsoff[is]], bgp[is] + pt * 32);
        }
    int cb = 0, sb = 2;
    for (int it = 0; it < 31; ++it) {
        asm volatile("s_waitcnt vmcnt(4)\n\ts_barrier" ::: "memory");
        if (it < 30) {
            int ktn = (it + 2) * 32;
#pragma unroll
            for (int is = 0; is < 2; ++is) {
                async16(&As[sb][ldsoff[is]], agp[is] + ktn);
                async16(&Bs[sb][ldsoff[is]], bgp[is] + ktn);
            }
        }
        kstep(As[cb], Bs[cb], acc, wm, wn, lhalf, slot);
        cb = (cb == 2) ? 0 : cb + 1;
        sb = (sb == 2) ? 0 : sb + 1;
    }
    asm volatile("s_waitcnt vmcnt(0)\n\ts_barrier" ::: "memory");
    kstep(As[cb], Bs[cb], acc, wm, wn, lhalf, slot);   // tile 31 (buf 31%3==1)

    // epilogue: + b1, relu, packed ushort4 stores (j = 4 consecutive cols)
    int hbase = prefix_cnt(cnt, e);
    const float* b1e = b1 + (size_t)e * OUT_DIM;
    int n0 = nt * 128 + wn * 64 + l15 * 4;
    float4 bias = *(const float4*)(b1e + n0);
#pragma unroll
    for (int i = 0; i < 4; ++i) {
        int m0 = mt * 128 + wm * 64 + i * 16 + quad * 4;
#pragma unroll
        for (int r = 0; r < 4; ++r) {
            int gm = m0 + r;
            if (gm < n_e) {
                float h0 = acc[i][0][r] + bias.x; h0 = h0 > 0.f ? h0 : 0.f;
                float h1 = acc[i][1][r] + bias.y; h1 = h1 > 0.f ? h1 : 0.f;
                float h2 = acc[i][2][r] + bias.z; h2 = h2 > 0.f ? h2 : 0.f;
                float h3 = acc[i][3][r] + bias.w; h3 = h3 > 0.f ? h3 : 0.f;
                ushort4 o;
                o.x = f2bf(h0); o.y = f2bf(h1); o.z = f2bf(h2); o.w = f2bf(h3);
                *(ushort4*)(H + (size_t)(hbase + gm) * OUT_DIM + n0) = o;
            }
        }
    }
}

// ---------------- GEMM2 (+fused combine): out[tok] += g*(H@W2 + b2) ---------
// R7: Y buffer and combine kernel eliminated. Epilogue scatters gated
// contributions via device-scope fp32 atomicAdd (cross-XCD coherent, m20).
// Each out element receives exactly 2 commutative adds -> bitwise
// deterministic; out zeroed by hipMemsetAsync at stream head.
__global__ __launch_bounds__(256) void gemm2_kernel(
    const unsigned short* __restrict__ H, const unsigned short* __restrict__ w2T,
    const float* __restrict__ b2, const int* __restrict__ bidx,
    const float2* __restrict__ gw, const int* __restrict__ cnt,
    float* __restrict__ out) {
    int b = blockIdx.x;
    int e = b & 7;
    int t2 = b >> 3;
    int nt = t2 & 7;
    int mt = t2 >> 3;
    int n_e = cnt[e];
    if (mt * 128 >= n_e) return;
    __shared__ __attribute__((aligned(16))) unsigned short As[3][64 * 64];
    __shared__ __attribute__((aligned(16))) unsigned short Bs[3][64 * 64];
    int t = threadIdx.x, wave = t >> 6, lane = t & 63;
    int hbase = prefix_cnt(cnt, e);
    const unsigned short* agp[2]; const unsigned short* bgp[2];
    int ldsoff[2];
#pragma unroll
    for (int is = 0; is < 2; ++is) {
        int c = is * 256 + t;
        int line = c >> 3;
        int chunkg = (c & 7) ^ (line & 7);
        int sub = chunkg >> 2;
        int growl = 2 * line + sub;
        int growlB = (line >> 5) * 64 + (line & 7) * 8 + sub * 4 + ((line >> 3) & 3);
        int gcol = (chunkg & 3) * 8;
        int gra = mt * 128 + growl;
        int grac = gra < n_e ? gra : n_e - 1;
        agp[is] = H + (size_t)(hbase + grac) * OUT_DIM + gcol;
        bgp[is] = w2T + ((size_t)e * OUT_DIM + nt * 128 + growlB) * OUT_DIM + gcol;
        ldsoff[is] = (is * 256 + wave * 64) * 8;
    }
    int wm = wave & 1, wn = wave >> 1;
    int quad = lane >> 4, l15 = lane & 15;
    int lhalf = l15 >> 1;
    int slot = (((l15 & 1) * 4 + quad) ^ lhalf) * 8;
    f32x4 zero4 = {0.f, 0.f, 0.f, 0.f};
    f32x4 acc[4][4];
#pragma unroll
    for (int i = 0; i < 4; ++i)
#pragma unroll
        for (int j = 0; j < 4; ++j) acc[i][j] = zero4;

#pragma unroll
    for (int pt = 0; pt < 2; ++pt)
#pragma unroll
        for (int is = 0; is < 2; ++is) {
            async16(&As[pt][ldsoff[is]], agp[is] + pt * 32);
            async16(&Bs[pt][ldsoff[is]], bgp[is] + pt * 32);
        }
    int cb = 0, sb = 2;
    for (int it = 0; it < 31; ++it) {
        asm volatile("s_waitcnt vmcnt(4)\n\ts_barrier" ::: "memory");
        if (it < 30) {
            int ktn = (it + 2) * 32;
#pragma unroll
            for (int is = 0; is < 2; ++is) {
                async16(&As[sb][ldsoff[is]], agp[is] + ktn);
                async16(&Bs[sb][ldsoff[is]], bgp[is] + ktn);
            }
        }
        kstep(As[cb], Bs[cb], acc, wm, wn, lhalf, slot);
        cb = (cb == 2) ? 0 : cb + 1;
        sb = (sb == 2) ? 0 : sb + 1;
    }
    asm volatile("s_waitcnt vmcnt(0)\n\ts_barrier" ::: "memory");
    kstep(As[cb], Bs[cb], acc, wm, wn, lhalf, slot);   // tile 31

    // fused-combine epilogue: gated atomic scatter (j = 4 consecutive cols)
    int n0 = nt * 128 + wn * 64 + l15 * 4;
    const float* b2e = b2 + (size_t)e * OUT_DIM;
    float4 bias = *(const float4*)(b2e + n0);
    const int* be = bidx + e * NTOK;
#pragma unroll
    for (int i = 0; i < 4; ++i) {
        int m0 = mt * 128 + wm * 64 + i * 16 + quad * 4;
#pragma unroll
        for (int r = 0; r < 4; ++r) {
            int gm = m0 + r;
            if (gm < n_e) {
                int v = be[gm];
                int tok = v & 0x7fff;
                float2 g2 = gw[tok];
                float g = (v >> 15) ? g2.y : g2.x;
                float* orow = out + (size_t)tok * OUT_DIM + n0;
                atomicAdd(orow + 0, g * (acc[i][0][r] + bias.x));
                atomicAdd(orow + 1, g * (acc[i][1][r] + bias.y));
                atomicAdd(orow + 2, g * (acc[i][2][r] + bias.z));
                atomicAdd(orow + 3, g * (acc[i][3][r] + bias.w));
            }
        }
    }
}

extern "C" void kernel_launch(void* const* d_in, const int* in_sizes, int n_in,
                              void* d_out, int out_size, void* d_ws, size_t ws_size,
                              hipStream_t stream) {
    const float* x  = (const float*)d_in[0];
    const float* rw = (const float*)d_in[1];
    const float* rb = (const float*)d_in[2];
    const float* w1 = (const float*)d_in[3];
    const float* b1 = (const float*)d_in[4];
    const float* w2 = (const float*)d_in[5];
    const float* b2 = (const float*)d_in[6];
    float* out = (float*)d_out;                       // fused [8192,1024]
    float* gating = out + (size_t)NTOK * OUT_DIM;     // gating [8192,8]

    char* ws = (char*)d_ws;
    // ws layout (bytes). Y eliminated (combine fused into gemm2).
    unsigned short* xb  = (unsigned short*)(ws + 0);          // 16 MiB
    unsigned short* w1T = (unsigned short*)(ws + 16777216);   // 16 MiB
    unsigned short* w2T = (unsigned short*)(ws + 33554432);   // 16 MiB
    unsigned short* H   = (unsigned short*)(ws + 50331648);   // 32 MiB
    int*   bidx  = (int*)(ws + 83886080);                     // 256 KiB
    int*   cnt   = (int*)(ws + 84213760);                     // 64 B
    int*    enc  = (int*)(ws + 84213888);                     // 32 KiB
    float2* gw   = (float2*)(ws + 84246656);                  // 64 KiB

    hipMemsetAsync(out, 0, (size_t)NTOK * OUT_DIM * sizeof(float), stream);
    convert_transpose_kernel<<<dim3(16, 16, 16), 256, 0, stream>>>(w1, w2, w1T, w2T);
    router_kernel<<<NTOK / 4, 256, 0, stream>>>(x, rw, rb, xb, gating, enc, gw, cnt);
    bucket_kernel<<<NTOK / 256, 256, 0, stream>>>(enc, bidx, cnt);
    gemm1_kernel<<<8 * 8 * MT_TILES, 256, 0, stream>>>(xb, w1T, b1, bidx, cnt, H);
    gemm2_kernel<<<8 * 8 * MT_TILES, 256, 0, stream>>>(H, w2T, b2, bidx, gw, cnt, out);
    (void)in_sizes; (void)n_in; (void)out_size; (void)ws_size;
}

// Round 8
// 285.939 us; speedup vs baseline: 1.6938x; 1.6938x over previous
//
#include <hip/hip_runtime.h>
#include <hip/hip_bf16.h>
#include <cstdint>
#include <cstddef>

#define IN_DIM 1024
#define OUT_DIM 1024
#define NE 8
#define NTOK 8192
#define MT_TILES 20   // 2560-row capacity per expert (counts ~2048+-42)
#define RBLK 512      // router blocks in prep_kernel (16 tokens each)

typedef __bf16 bf16x8 __attribute__((ext_vector_type(8)));
typedef float f32x4 __attribute__((ext_vector_type(4)));
typedef unsigned short ushort8v __attribute__((ext_vector_type(8)));

// RNE float -> bf16 bits
__device__ __forceinline__ unsigned short f2bf(float f) {
    unsigned u = __float_as_uint(f);
    unsigned r = 0x7fffu + ((u >> 16) & 1u);
    return (unsigned short)((u + r) >> 16);
}

// decode packed bf16 pair (u32) -> two floats
__device__ __forceinline__ void bf2x(unsigned u, float& lo, float& hi) {
    lo = __uint_as_float(u << 16);
    hi = __uint_as_float(u & 0xffff0000u);
}

// async global->LDS, 16B per lane. lds must be wave-uniform base; g is per-lane.
__device__ __forceinline__ void async16(void* lds, const void* g) {
    __builtin_amdgcn_global_load_lds(
        (const __attribute__((address_space(1))) unsigned int*)g,
        (__attribute__((address_space(3))) unsigned int*)lds,
        16, 0, 0);
}

// ---------------- prep: fused router (blocks 0..511) + weight convert -------
// R8: convert_transpose (deps: w1,w2) and router (deps: x,rw) are
// independent; one launch with block-range split overlaps them on the CU
// array (wall ~= max instead of sum). Router widened to 16 tokens/block:
// the 32 KB rw panel staging is amortized 4x (was per-4-tokens).
// Shared LDS arena: router uses 32 KB srw; convert uses 64x69 f32 tile.
__global__ __launch_bounds__(256) void prep_kernel(
    const float* __restrict__ w1, const float* __restrict__ w2,
    unsigned short* __restrict__ w1T, unsigned short* __restrict__ w2T,
    const float* __restrict__ x, const float* __restrict__ rw,
    const float* __restrict__ rb,
    unsigned short* __restrict__ xb,
    float* __restrict__ gating, int* __restrict__ enc,
    float2* __restrict__ gw, int* __restrict__ cnt) {
    __shared__ float lds_f[NE * IN_DIM];   // 32 KB arena (router srw / conv tile)
    int b = blockIdx.x;
    int t = threadIdx.x;
    if (b < RBLK) {
        // ---------------- router block: 16 tokens ----------------
        float* srw = lds_f;                 // srw[e*1024 + k]
        if (b == 0 && t < NE) cnt[t] = 0;   // zero counters for bucket
#pragma unroll
        for (int i = 0; i < 4; ++i) {
            int k = t + i * 256;
            float4 a = *(const float4*)(rw + (size_t)k * NE);
            float4 bq = *(const float4*)(rw + (size_t)k * NE + 4);
            srw[0 * IN_DIM + k] = a.x;  srw[1 * IN_DIM + k] = a.y;
            srw[2 * IN_DIM + k] = a.z;  srw[3 * IN_DIM + k] = a.w;
            srw[4 * IN_DIM + k] = bq.x; srw[5 * IN_DIM + k] = bq.y;
            srw[6 * IN_DIM + k] = bq.z; srw[7 * IN_DIM + k] = bq.w;
        }
        __syncthreads();
        int wave = t >> 6, lane = t & 63;
        for (int tt = 0; tt < 4; ++tt) {
            int tok = b * 16 + wave * 4 + tt;
            const float* xrow = x + (size_t)tok * IN_DIM;
            unsigned short* xbrow = xb + (size_t)tok * IN_DIM;
            float acc[NE] = {0, 0, 0, 0, 0, 0, 0, 0};
#pragma unroll
            for (int i = 0; i < 4; ++i) {
                int k = i * 256 + lane * 4;
                float4 xv = *(const float4*)(xrow + k);
                ushort4 o;
                o.x = f2bf(xv.x); o.y = f2bf(xv.y); o.z = f2bf(xv.z); o.w = f2bf(xv.w);
                *(ushort4*)(xbrow + k) = o;
#pragma unroll
                for (int e = 0; e < NE; ++e) {
                    float4 wv = *(const float4*)(srw + e * IN_DIM + k);
                    acc[e] = fmaf(xv.x, wv.x, fmaf(xv.y, wv.y, fmaf(xv.z, wv.z, fmaf(xv.w, wv.w, acc[e]))));
                }
            }
#pragma unroll
            for (int e = 0; e < NE; ++e) {
#pragma unroll
                for (int off = 32; off > 0; off >>= 1) acc[e] += __shfl_xor(acc[e], off);
                acc[e] += rb[e];
            }
            // top-2 (lowest index wins ties, matching lax.top_k)
            int e0 = 0; float v0 = acc[0];
#pragma unroll
            for (int e = 1; e < NE; ++e) if (acc[e] > v0) { v0 = acc[e]; e0 = e; }
            int e1 = -1; float v1 = -3.4e38f;
#pragma unroll
            for (int e = 0; e < NE; ++e) if (e != e0 && acc[e] > v1) { v1 = acc[e]; e1 = e; }
            float tg = __expf(v1 - v0);
            float inv = 1.0f / (1.0f + tg);
            float g0 = inv, g1 = tg * inv;
            if (lane < NE) gating[(size_t)tok * NE + lane] = (lane == e0) ? g0 : ((lane == e1) ? g1 : 0.0f);
            if (lane == 0) {
                enc[tok] = e0 | (e1 << 8);
                gw[tok] = make_float2(g0, g1);
            }
        }
    } else {
        // ---------------- convert block: one 64x64 tile ----------------
        // R5-polished body: pad-69 LDS (2-way bank aliasing on transpose
        // read), 8-threads-per-output-row contiguous 128B writes.
        int cb = b - RBLK;                  // 0..4095
        int z = cb >> 8;                    // 0..15
        int kt = ((cb >> 4) & 15) * 64, nt = (cb & 15) * 64;
        const float* src = (z < 8) ? (w1 + (size_t)z * IN_DIM * OUT_DIM)
                                   : (w2 + (size_t)(z - 8) * OUT_DIM * OUT_DIM);
        unsigned short* dst = (z < 8) ? (w1T + (size_t)z * IN_DIM * OUT_DIM)
                                      : (w2T + (size_t)(z - 8) * OUT_DIM * OUT_DIM);
        float* tile = lds_f;                // tile[r][c] = tile[r*69+c]
        int r = t >> 2, cq = (t & 3) * 16;
#pragma unroll
        for (int q = 0; q < 4; ++q) {
            float4 v = *(const float4*)(src + (size_t)(kt + r) * 1024 + nt + cq + q * 4);
            tile[r * 69 + cq + q * 4 + 0] = v.x;
            tile[r * 69 + cq + q * 4 + 1] = v.y;
            tile[r * 69 + cq + q * 4 + 2] = v.z;
            tile[r * 69 + cq + q * 4 + 3] = v.w;
        }
        __syncthreads();
        int n2 = t >> 3, k8 = (t & 7) * 8;
#pragma unroll
        for (int q = 0; q < 2; ++q) {
            int n = n2 + q * 32;
            ushort8v o;
#pragma unroll
            for (int i = 0; i < 8; ++i) o[i] = f2bf(tile[(k8 + i) * 69 + n]);
            *(ushort8v*)(dst + (size_t)(nt + n) * 1024 + kt + k8) = o;
        }
    }
}

// ---------------- bucket: wave-aggregated atomic compaction ------------------
__global__ __launch_bounds__(256) void bucket_kernel(
    const int* __restrict__ enc,
    int* __restrict__ bidx, int* __restrict__ slots, int* __restrict__ cnt) {
    int tok = blockIdx.x * 256 + threadIdx.x;
    int lane = threadIdx.x & 63;
    int v = enc[tok];
    int e0 = v & 0xff, e1 = (v >> 8) & 0xff;
    unsigned long long below = (1ull << lane) - 1ull;
    int p0 = 0, p1 = 0;
#pragma unroll
    for (int e = 0; e < NE; ++e) {
        unsigned long long m0 = __ballot(e0 == e);
        unsigned long long m1 = __ballot(e1 == e);
        int c0 = __popcll(m0), c1 = __popcll(m1);
        int base = 0;
        if (lane == 0 && (c0 + c1)) base = atomicAdd(&cnt[e], c0 + c1);
        base = __shfl(base, 0);
        if (e0 == e) p0 = base + __popcll(m0 & below);
        if (e1 == e) p1 = base + c0 + __popcll(m1 & below);
    }
    bidx[e0 * NTOK + p0] = tok;
    bidx[e1 * NTOK + p1] = tok;
    slots[2 * tok + 0] = (e0 << 13) | p0;
    slots[2 * tok + 1] = (e1 << 13) | p1;
}

// inline 8-entry exclusive prefix of cnt up to e (uniform scalar loads)
__device__ __forceinline__ int prefix_cnt(const int* __restrict__ cnt, int e) {
    int s = 0;
    for (int i = 0; i < NE; ++i) s += (i < e) ? cnt[i] : 0;
    return s;
}

// ---------------- GEMM K-step: ds_read fragments + 16 MFMA ------------------
__device__ __forceinline__ void kstep(const unsigned short* Ab,
                                      const unsigned short* Bb,
                                      f32x4 (&acc)[4][4], int wm, int wn,
                                      int lhalf, int slot) {
    bf16x8 av[4], bv[4];
#pragma unroll
    for (int i = 0; i < 4; ++i)
        av[i] = *(const bf16x8*)(Ab + (wm * 32 + i * 8 + lhalf) * 64 + slot);
#pragma unroll
    for (int j = 0; j < 4; ++j)
        bv[j] = *(const bf16x8*)(Bb + (wn * 32 + j * 8 + lhalf) * 64 + slot);
#pragma unroll
    for (int i = 0; i < 4; ++i)
#pragma unroll
        for (int j = 0; j < 4; ++j)
            acc[i][j] = __builtin_amdgcn_mfma_f32_16x16x32_bf16(av[i], bv[j], acc[i][j], 0, 0, 0);
}

// ---------------- GEMM K-loop (shared by gemm1/gemm2) -----------------------
// R6-verified structure (66/64.5 us): 128x128 tile, BK=32, THREE LDS buffers
// (48 KB -> 3 blocks/CU = 12 waves/CU), depth-2 counted vmcnt(4).
// Plateau ledger (R0-R4): >=12 waves/CU => ~65 us regardless of drain vs
// counted vs LDS traffic; <12 waves/CU regresses. R7: fused atomic-scatter
// epilogue = 8x write amplification (atomics write through ~16B/op) -- never
// replace coalesced streaming stores with per-element global atomics.
// LDS layout per buffer: 64 lines x 128B; line L packs 2 rows (32 K-elems
// each) as 8 chunks of 16B, XOR-swizzled: slot = chunk ^ (L&7).
// B-row PERMUTATION (R0): B staged so fragment (j,l15) = output column
// n = wn*64 + 4*l15 + j  -> epilogue j=0..3 are 4 consecutive columns.

// ---------------- GEMM1: H = relu(gather(Xb) @ W1 + b1), bf16 out ----------
__global__ __launch_bounds__(256) void gemm1_kernel(
    const unsigned short* __restrict__ xb, const unsigned short* __restrict__ w1T,
    const float* __restrict__ b1, const int* __restrict__ bidx,
    const int* __restrict__ cnt,
    unsigned short* __restrict__ H) {
    int b = blockIdx.x;
    int e = b & 7;          // XCD pin: all of expert e on XCD e
    int t2 = b >> 3;
    int nt = t2 & 7;
    int mt = t2 >> 3;
    int n_e = cnt[e];
    if (mt * 128 >= n_e) return;
    __shared__ __attribute__((aligned(16))) unsigned short As[3][64 * 64];
    __shared__ __attribute__((aligned(16))) unsigned short Bs[3][64 * 64];
    int t = threadIdx.x, wave = t >> 6, lane = t & 63;
    const int* be = bidx + e * NTOK;
    const unsigned short* agp[2]; const unsigned short* bgp[2];
    int ldsoff[2];
#pragma unroll
    for (int is = 0; is < 2; ++is) {
        int c = is * 256 + t;
        int line = c >> 3;
        int chunkg = (c & 7) ^ (line & 7);
        int sub = chunkg >> 2;
        int growl = 2 * line + sub;                       // A row (unchanged)
        int growlB = (line >> 5) * 64 + (line & 7) * 8 + sub * 4 + ((line >> 3) & 3);
        int gcol = (chunkg & 3) * 8;
        int gra = mt * 128 + growl;
        int grac = gra < n_e ? gra : n_e - 1;
        agp[is] = xb + (size_t)be[grac] * IN_DIM + gcol;
        bgp[is] = w1T + ((size_t)e * OUT_DIM + nt * 128 + growlB) * IN_DIM + gcol;
        ldsoff[is] = (is * 256 + wave * 64) * 8; // elements; lane*16B appended by HW
    }
    int wm = wave & 1, wn = wave >> 1;
    int quad = lane >> 4, l15 = lane & 15;
    int lhalf = l15 >> 1;                       // = line&7 for all frags
    int slot = (((l15 & 1) * 4 + quad) ^ lhalf) * 8; // element offset in line
    f32x4 zero4 = {0.f, 0.f, 0.f, 0.f};
    f32x4 acc[4][4];
#pragma unroll
    for (int i = 0; i < 4; ++i)
#pragma unroll
        for (int j = 0; j < 4; ++j) acc[i][j] = zero4;

    // prologue: stage k-tiles 0..1 into buffers 0..1 (8 loads/wave in flight)
#pragma unroll
    for (int pt = 0; pt < 2; ++pt)
#pragma unroll
        for (int is = 0; is < 2; ++is) {
            async16(&As[pt][ldsoff[is]], agp[is] + pt * 32);
            async16(&Bs[pt][ldsoff[is]], bgp[is] + pt * 32);
        }
    int cb = 0, sb = 2;
    for (int it = 0; it < 31; ++it) {
        asm volatile("s_waitcnt vmcnt(4)\n\ts_barrier" ::: "memory");
        if (it < 30) {
            int ktn = (it + 2) * 32;
#pragma unroll
            for (int is = 0; is < 2; ++is) {
                async16(&As[sb][ldsoff[is]], agp[is] + ktn);
                async16(&Bs[sb][ldsoff[is]], bgp[is] + ktn);
            }
        }
        kstep(As[cb], Bs[cb], acc, wm, wn, lhalf, slot);
        cb = (cb == 2) ? 0 : cb + 1;
        sb = (sb == 2) ? 0 : sb + 1;
    }
    asm volatile("s_waitcnt vmcnt(0)\n\ts_barrier" ::: "memory");
    kstep(As[cb], Bs[cb], acc, wm, wn, lhalf, slot);   // tile 31 (buf 31%3==1)

    // epilogue: + b1, relu, packed ushort4 stores (j = 4 consecutive cols)
    int hbase = prefix_cnt(cnt, e);
    const float* b1e = b1 + (size_t)e * OUT_DIM;
    int n0 = nt * 128 + wn * 64 + l15 * 4;
    float4 bias = *(const float4*)(b1e + n0);
#pragma unroll
    for (int i = 0; i < 4; ++i) {
        int m0 = mt * 128 + wm * 64 + i * 16 + quad * 4;
#pragma unroll
        for (int r = 0; r < 4; ++r) {
            int gm = m0 + r;
            if (gm < n_e) {
                float h0 = acc[i][0][r] + bias.x; h0 = h0 > 0.f ? h0 : 0.f;
                float h1 = acc[i][1][r] + bias.y; h1 = h1 > 0.f ? h1 : 0.f;
                float h2 = acc[i][2][r] + bias.z; h2 = h2 > 0.f ? h2 : 0.f;
                float h3 = acc[i][3][r] + bias.w; h3 = h3 > 0.f ? h3 : 0.f;
                ushort4 o;
                o.x = f2bf(h0); o.y = f2bf(h1); o.z = f2bf(h2); o.w = f2bf(h3);
                *(ushort4*)(H + (size_t)(hbase + gm) * OUT_DIM + n0) = o;
            }
        }
    }
}

// ---------------- GEMM2: Y = H @ W2 (packed bf16, packed stores) ------------
__global__ __launch_bounds__(256) void gemm2_kernel(
    const unsigned short* __restrict__ H, const unsigned short* __restrict__ w2T,
    const int* __restrict__ cnt,
    unsigned short* __restrict__ Y) {
    int b = blockIdx.x;
    int e = b & 7;
    int t2 = b >> 3;
    int nt = t2 & 7;
    int mt = t2 >> 3;
    int n_e = cnt[e];
    if (mt * 128 >= n_e) return;
    __shared__ __attribute__((aligned(16))) unsigned short As[3][64 * 64];
    __shared__ __attribute__((aligned(16))) unsigned short Bs[3][64 * 64];
    int t = threadIdx.x, wave = t >> 6, lane = t & 63;
    int hbase = prefix_cnt(cnt, e);
    const unsigned short* agp[2]; const unsigned short* bgp[2];
    int ldsoff[2];
#pragma unroll
    for (int is = 0; is < 2; ++is) {
        int c = is * 256 + t;
        int line = c >> 3;
        int chunkg = (c & 7) ^ (line & 7);
        int sub = chunkg >> 2;
        int growl = 2 * line + sub;
        int growlB = (line >> 5) * 64 + (line & 7) * 8 + sub * 4 + ((line >> 3) & 3);
        int gcol = (chunkg & 3) * 8;
        int gra = mt * 128 + growl;
        int grac = gra < n_e ? gra : n_e - 1;
        agp[is] = H + (size_t)(hbase + grac) * OUT_DIM + gcol;
        bgp[is] = w2T + ((size_t)e * OUT_DIM + nt * 128 + growlB) * OUT_DIM + gcol;
        ldsoff[is] = (is * 256 + wave * 64) * 8;
    }
    int wm = wave & 1, wn = wave >> 1;
    int quad = lane >> 4, l15 = lane & 15;
    int lhalf = l15 >> 1;
    int slot = (((l15 & 1) * 4 + quad) ^ lhalf) * 8;
    f32x4 zero4 = {0.f, 0.f, 0.f, 0.f};
    f32x4 acc[4][4];
#pragma unroll
    for (int i = 0; i < 4; ++i)
#pragma unroll
        for (int j = 0; j < 4; ++j) acc[i][j] = zero4;

#pragma unroll
    for (int pt = 0; pt < 2; ++pt)
#pragma unroll
        for (int is = 0; is < 2; ++is) {
            async16(&As[pt][ldsoff[is]], agp[is] + pt * 32);
            async16(&Bs[pt][ldsoff[is]], bgp[is] + pt * 32);
        }
    int cb = 0, sb = 2;
    for (int it = 0; it < 31; ++it) {
        asm volatile("s_waitcnt vmcnt(4)\n\ts_barrier" ::: "memory");
        if (it < 30) {
            int ktn = (it + 2) * 32;
#pragma unroll
            for (int is = 0; is < 2; ++is) {
                async16(&As[sb][ldsoff[is]], agp[is] + ktn);
                async16(&Bs[sb][ldsoff[is]], bgp[is] + ktn);
            }
        }
        kstep(As[cb], Bs[cb], acc, wm, wn, lhalf, slot);
        cb = (cb == 2) ? 0 : cb + 1;
        sb = (sb == 2) ? 0 : sb + 1;
    }
    asm volatile("s_waitcnt vmcnt(0)\n\ts_barrier" ::: "memory");
    kstep(As[cb], Bs[cb], acc, wm, wn, lhalf, slot);   // tile 31

    // epilogue: packed ushort4 bf16 stores to packed Y
    int n0 = nt * 128 + wn * 64 + l15 * 4;
#pragma unroll
    for (int i = 0; i < 4; ++i) {
        int m0 = mt * 128 + wm * 64 + i * 16 + quad * 4;
#pragma unroll
        for (int r = 0; r < 4; ++r) {
            int gm = m0 + r;
            if (gm < n_e) {
                ushort4 o;
                o.x = f2bf(acc[i][0][r]); o.y = f2bf(acc[i][1][r]);
                o.z = f2bf(acc[i][2][r]); o.w = f2bf(acc[i][3][r]);
                *(ushort4*)(Y + (size_t)(hbase + gm) * OUT_DIM + n0) = o;
            }
        }
    }
}

// ---------------- combine: out[tok] = g0*(Y[r0]+b2[e0]) + g1*(Y[r1]+b2[e1]) -
__global__ __launch_bounds__(256) void combine_kernel(
    const unsigned short* __restrict__ Y, const float* __restrict__ b2,
    const float2* __restrict__ gw, const int* __restrict__ slots,
    const int* __restrict__ cnt, float* __restrict__ out) {
    int t = threadIdx.x, wave = t >> 6, lane = t & 63;
    int tok = blockIdx.x * 4 + wave;
    int pre[NE];
    {
        int s = 0;
#pragma unroll
        for (int i = 0; i < NE; ++i) { pre[i] = s; s += cnt[i]; }
    }
    int s0 = slots[2 * tok], s1 = slots[2 * tok + 1];
    int e0 = s0 >> 13, e1 = s1 >> 13;
    int r0 = pre[e0] + (s0 & 8191);
    int r1 = pre[e1] + (s1 & 8191);
    float2 g = gw[tok];
    const unsigned short* y0 = Y + (size_t)r0 * OUT_DIM;
    const unsigned short* y1 = Y + (size_t)r1 * OUT_DIM;
    const float* c0 = b2 + (size_t)e0 * OUT_DIM;
    const float* c1 = b2 + (size_t)e1 * OUT_DIM;
    float* orow = out + (size_t)tok * OUT_DIM;
#pragma unroll
    for (int i = 0; i < 2; ++i) {
        int c = i * 512 + lane * 8;
        uint4 ua = *(const uint4*)(y0 + c);
        uint4 ub = *(const uint4*)(y1 + c);
        float a[8], b[8];
        bf2x(ua.x, a[0], a[1]); bf2x(ua.y, a[2], a[3]);
        bf2x(ua.z, a[4], a[5]); bf2x(ua.w, a[6], a[7]);
        bf2x(ub.x, b[0], b[1]); bf2x(ub.y, b[2], b[3]);
        bf2x(ub.z, b[4], b[5]); bf2x(ub.w, b[6], b[7]);
        float4 p0 = *(const float4*)(c0 + c);
        float4 p1 = *(const float4*)(c0 + c + 4);
        float4 q0 = *(const float4*)(c1 + c);
        float4 q1 = *(const float4*)(c1 + c + 4);
        float o[8];
        o[0] = g.x * (a[0] + p0.x) + g.y * (b[0] + q0.x);
        o[1] = g.x * (a[1] + p0.y) + g.y * (b[1] + q0.y);
        o[2] = g.x * (a[2] + p0.z) + g.y * (b[2] + q0.z);
        o[3] = g.x * (a[3] + p0.w) + g.y * (b[3] + q0.w);
        o[4] = g.x * (a[4] + p1.x) + g.y * (b[4] + q1.x);
        o[5] = g.x * (a[5] + p1.y) + g.y * (b[5] + q1.y);
        o[6] = g.x * (a[6] + p1.z) + g.y * (b[6] + q1.z);
        o[7] = g.x * (a[7] + p1.w) + g.y * (b[7] + q1.w);
        *(float4*)(orow + c) = make_float4(o[0], o[1], o[2], o[3]);
        *(float4*)(orow + c + 4) = make_float4(o[4], o[5], o[6], o[7]);
    }
}

extern "C" void kernel_launch(void* const* d_in, const int* in_sizes, int n_in,
                              void* d_out, int out_size, void* d_ws, size_t ws_size,
                              hipStream_t stream) {
    const float* x  = (const float*)d_in[0];
    const float* rw = (const float*)d_in[1];
    const float* rb = (const float*)d_in[2];
    const float* w1 = (const float*)d_in[3];
    const float* b1 = (const float*)d_in[4];
    const float* w2 = (const float*)d_in[5];
    const float* b2 = (const float*)d_in[6];
    float* out = (float*)d_out;                       // fused [8192,1024]
    float* gating = out + (size_t)NTOK * OUT_DIM;     // gating [8192,8]

    char* ws = (char*)d_ws;
    // ws layout (bytes). Y reuses [0,32MiB): xb+w1T dead after gemm1
    // (stream-ordered). enc/gw outside H region.
    unsigned short* xb  = (unsigned short*)(ws + 0);          // 16 MiB
    unsigned short* Y   = (unsigned short*)(ws + 0);          // 32 MiB (gemm2+)
    unsigned short* w1T = (unsigned short*)(ws + 16777216);   // 16 MiB
    unsigned short* w2T = (unsigned short*)(ws + 33554432);   // 16 MiB
    unsigned short* H   = (unsigned short*)(ws + 50331648);   // 32 MiB
    int*   bidx  = (int*)(ws + 83886080);                     // 256 KiB
    int*   slots = (int*)(ws + 84148224);                     // 64 KiB
    int*   cnt   = (int*)(ws + 84213760);                     // 64 B
    int*    enc  = (int*)(ws + 84213888);                     // 32 KiB
    float2* gw   = (float2*)(ws + 84246656);                  // 64 KiB

    prep_kernel<<<RBLK + 16 * 16 * 16, 256, 0, stream>>>(
        w1, w2, w1T, w2T, x, rw, rb, xb, gating, enc, gw, cnt);
    bucket_kernel<<<NTOK / 256, 256, 0, stream>>>(enc, bidx, slots, cnt);
    gemm1_kernel<<<8 * 8 * MT_TILES, 256, 0, stream>>>(xb, w1T, b1, bidx, cnt, H);
    gemm2_kernel<<<8 * 8 * MT_TILES, 256, 0, stream>>>(H, w2T, cnt, Y);
    combine_kernel<<<NTOK / 4, 256, 0, stream>>>(Y, b2, gw, slots, cnt, out);
    (void)in_sizes; (void)n_in; (void)out_size; (void)ws_size;
}

// Round 9
// 278.973 us; speedup vs baseline: 1.7361x; 1.0250x over previous
//
#include <hip/hip_runtime.h>
#include <hip/hip_bf16.h>
#include <cstdint>
#include <cstddef>

#define IN_DIM 1024
#define OUT_DIM 1024
#define NE 8
#define NTOK 8192
#define MT_TILES 20   // 2560-row capacity per expert (counts ~2048+-42)
#define RBLK 512      // router blocks in prep_kernel (16 tokens each)

typedef __bf16 bf16x8 __attribute__((ext_vector_type(8)));
typedef float f32x4 __attribute__((ext_vector_type(4)));
typedef unsigned short ushort8v __attribute__((ext_vector_type(8)));

// RNE float -> bf16 bits
__device__ __forceinline__ unsigned short f2bf(float f) {
    unsigned u = __float_as_uint(f);
    unsigned r = 0x7fffu + ((u >> 16) & 1u);
    return (unsigned short)((u + r) >> 16);
}

// decode packed bf16 pair (u32) -> two floats
__device__ __forceinline__ void bf2x(unsigned u, float& lo, float& hi) {
    lo = __uint_as_float(u << 16);
    hi = __uint_as_float(u & 0xffff0000u);
}

// async global->LDS, 16B per lane. lds must be wave-uniform base; g is per-lane.
__device__ __forceinline__ void async16(void* lds, const void* g) {
    __builtin_amdgcn_global_load_lds(
        (const __attribute__((address_space(1))) unsigned int*)g,
        (__attribute__((address_space(3))) unsigned int*)lds,
        16, 0, 0);
}

// ---- convert one 64x64 tile: [K][N] fp32 -> [N][K] bf16 (R5-polished) ------
// pad-69 LDS (transpose-read stride 16x69 = 16 mod 32 -> 2-way bank aliasing,
// free) + 8-threads-per-output-row contiguous 128B writes.
__device__ __forceinline__ void convert_tile(
    const float* __restrict__ src, unsigned short* __restrict__ dst,
    int kt, int nt, int t, float* tile /* [64*69] */) {
    int r = t >> 2, cq = (t & 3) * 16;
#pragma unroll
    for (int q = 0; q < 4; ++q) {
        float4 v = *(const float4*)(src + (size_t)(kt + r) * 1024 + nt + cq + q * 4);
        tile[r * 69 + cq + q * 4 + 0] = v.x;
        tile[r * 69 + cq + q * 4 + 1] = v.y;
        tile[r * 69 + cq + q * 4 + 2] = v.z;
        tile[r * 69 + cq + q * 4 + 3] = v.w;
    }
    __syncthreads();
    int n2 = t >> 3, k8 = (t & 7) * 8;
#pragma unroll
    for (int q = 0; q < 2; ++q) {
        int n = n2 + q * 32;
        ushort8v o;
#pragma unroll
        for (int i = 0; i < 8; ++i) o[i] = f2bf(tile[(k8 + i) * 69 + n]);
        *(ushort8v*)(dst + (size_t)(nt + n) * 1024 + kt + k8) = o;
    }
}

// ---------------- prep: fused router (blocks 0..511) + w1 convert -----------
// R8: router and w1-convert are independent; one launch, block-range split,
// wall ~= max instead of sum. Router: 16 tokens/block (rw staging amortized).
// R9: w2-convert moved OUT (to the bucket launch) -- w2T isn't needed until
// gemm2, so it rides the bucket launch's idle CUs instead of prep's critical
// path.
__global__ __launch_bounds__(256) void prep_kernel(
    const float* __restrict__ w1, unsigned short* __restrict__ w1T,
    const float* __restrict__ x, const float* __restrict__ rw,
    const float* __restrict__ rb,
    unsigned short* __restrict__ xb,
    float* __restrict__ gating, int* __restrict__ enc,
    float2* __restrict__ gw, int* __restrict__ cnt) {
    __shared__ float lds_f[NE * IN_DIM];   // 32 KB arena (router srw / conv tile)
    int b = blockIdx.x;
    int t = threadIdx.x;
    if (b < RBLK) {
        // ---------------- router block: 16 tokens ----------------
        float* srw = lds_f;                 // srw[e*1024 + k]
        if (b == 0 && t < NE) cnt[t] = 0;   // zero counters for bucket
#pragma unroll
        for (int i = 0; i < 4; ++i) {
            int k = t + i * 256;
            float4 a = *(const float4*)(rw + (size_t)k * NE);
            float4 bq = *(const float4*)(rw + (size_t)k * NE + 4);
            srw[0 * IN_DIM + k] = a.x;  srw[1 * IN_DIM + k] = a.y;
            srw[2 * IN_DIM + k] = a.z;  srw[3 * IN_DIM + k] = a.w;
            srw[4 * IN_DIM + k] = bq.x; srw[5 * IN_DIM + k] = bq.y;
            srw[6 * IN_DIM + k] = bq.z; srw[7 * IN_DIM + k] = bq.w;
        }
        __syncthreads();
        int wave = t >> 6, lane = t & 63;
        for (int tt = 0; tt < 4; ++tt) {
            int tok = b * 16 + wave * 4 + tt;
            const float* xrow = x + (size_t)tok * IN_DIM;
            unsigned short* xbrow = xb + (size_t)tok * IN_DIM;
            float acc[NE] = {0, 0, 0, 0, 0, 0, 0, 0};
#pragma unroll
            for (int i = 0; i < 4; ++i) {
                int k = i * 256 + lane * 4;
                float4 xv = *(const float4*)(xrow + k);
                ushort4 o;
                o.x = f2bf(xv.x); o.y = f2bf(xv.y); o.z = f2bf(xv.z); o.w = f2bf(xv.w);
                *(ushort4*)(xbrow + k) = o;
#pragma unroll
                for (int e = 0; e < NE; ++e) {
                    float4 wv = *(const float4*)(srw + e * IN_DIM + k);
                    acc[e] = fmaf(xv.x, wv.x, fmaf(xv.y, wv.y, fmaf(xv.z, wv.z, fmaf(xv.w, wv.w, acc[e]))));
                }
            }
#pragma unroll
            for (int e = 0; e < NE; ++e) {
#pragma unroll
                for (int off = 32; off > 0; off >>= 1) acc[e] += __shfl_xor(acc[e], off);
                acc[e] += rb[e];
            }
            // top-2 (lowest index wins ties, matching lax.top_k)
            int e0 = 0; float v0 = acc[0];
#pragma unroll
            for (int e = 1; e < NE; ++e) if (acc[e] > v0) { v0 = acc[e]; e0 = e; }
            int e1 = -1; float v1 = -3.4e38f;
#pragma unroll
            for (int e = 0; e < NE; ++e) if (e != e0 && acc[e] > v1) { v1 = acc[e]; e1 = e; }
            float tg = __expf(v1 - v0);
            float inv = 1.0f / (1.0f + tg);
            float g0 = inv, g1 = tg * inv;
            if (lane < NE) gating[(size_t)tok * NE + lane] = (lane == e0) ? g0 : ((lane == e1) ? g1 : 0.0f);
            if (lane == 0) {
                enc[tok] = e0 | (e1 << 8);
                gw[tok] = make_float2(g0, g1);
            }
        }
    } else {
        // ---------------- w1 convert block: one 64x64 tile ----------------
        int cb = b - RBLK;                  // 0..2047
        int z = cb >> 8;                    // 0..7
        int kt = ((cb >> 4) & 15) * 64, nt = (cb & 15) * 64;
        convert_tile(w1 + (size_t)z * IN_DIM * OUT_DIM,
                     w1T + (size_t)z * IN_DIM * OUT_DIM, kt, nt, t, lds_f);
    }
}

// ---------------- bucket (blocks 0..31) + w2 convert (blocks 32..2079) ------
// Bucket is 32 blocks of ballot-scan; the other 248+ CUs were idle for the
// whole launch slot -- fill them with the w2 conversion (needed only by
// gemm2, two launches later).
__global__ __launch_bounds__(256) void bucket_kernel(
    const int* __restrict__ enc,
    int* __restrict__ bidx, int* __restrict__ slots, int* __restrict__ cnt,
    const float* __restrict__ w2, unsigned short* __restrict__ w2T) {
    int b = blockIdx.x;
    int t = threadIdx.x;
    if (b < NTOK / 256) {
        int tok = b * 256 + t;
        int lane = t & 63;
        int v = enc[tok];
        int e0 = v & 0xff, e1 = (v >> 8) & 0xff;
        unsigned long long below = (1ull << lane) - 1ull;
        int p0 = 0, p1 = 0;
#pragma unroll
        for (int e = 0; e < NE; ++e) {
            unsigned long long m0 = __ballot(e0 == e);
            unsigned long long m1 = __ballot(e1 == e);
            int c0 = __popcll(m0), c1 = __popcll(m1);
            int base = 0;
            if (lane == 0 && (c0 + c1)) base = atomicAdd(&cnt[e], c0 + c1);
            base = __shfl(base, 0);
            if (e0 == e) p0 = base + __popcll(m0 & below);
            if (e1 == e) p1 = base + c0 + __popcll(m1 & below);
        }
        bidx[e0 * NTOK + p0] = tok;
        bidx[e1 * NTOK + p1] = tok;
        slots[2 * tok + 0] = (e0 << 13) | p0;
        slots[2 * tok + 1] = (e1 << 13) | p1;
    } else {
        __shared__ float tile[64 * 69];
        int cb = b - NTOK / 256;            // 0..2047
        int z = cb >> 8;                    // 0..7
        int kt = ((cb >> 4) & 15) * 64, nt = (cb & 15) * 64;
        convert_tile(w2 + (size_t)z * OUT_DIM * OUT_DIM,
                     w2T + (size_t)z * OUT_DIM * OUT_DIM, kt, nt, t, tile);
    }
}

// inline 8-entry exclusive prefix of cnt up to e (uniform scalar loads)
__device__ __forceinline__ int prefix_cnt(const int* __restrict__ cnt, int e) {
    int s = 0;
    for (int i = 0; i < NE; ++i) s += (i < e) ? cnt[i] : 0;
    return s;
}

// ---------------- GEMM K-step: ds_read fragments + 16 MFMA ------------------
__device__ __forceinline__ void kstep(const unsigned short* Ab,
                                      const unsigned short* Bb,
                                      f32x4 (&acc)[4][4], int wm, int wn,
                                      int lhalf, int slot) {
    bf16x8 av[4], bv[4];
#pragma unroll
    for (int i = 0; i < 4; ++i)
        av[i] = *(const bf16x8*)(Ab + (wm * 32 + i * 8 + lhalf) * 64 + slot);
#pragma unroll
    for (int j = 0; j < 4; ++j)
        bv[j] = *(const bf16x8*)(Bb + (wn * 32 + j * 8 + lhalf) * 64 + slot);
#pragma unroll
    for (int i = 0; i < 4; ++i)
#pragma unroll
        for (int j = 0; j < 4; ++j)
            acc[i][j] = __builtin_amdgcn_mfma_f32_16x16x32_bf16(av[i], bv[j], acc[i][j], 0, 0, 0);
}

// ---------------- GEMM K-loop (shared by gemm1/gemm2) -----------------------
// R6-verified structure (65/64.5 us): 128x128 tile, BK=32, THREE LDS buffers
// (48 KB -> 3 blocks/CU = 12 waves/CU), depth-2 counted vmcnt(4).
// Plateau ledger (R0-R4): >=12 waves/CU => ~65 us regardless of drain vs
// counted vs LDS traffic; <12 waves/CU regresses. R7: per-element global
// atomics = 8x write amplification -- never replace coalesced streaming
// stores with atomic scatter.
// LDS layout per buffer: 64 lines x 128B; line L packs 2 rows (32 K-elems
// each) as 8 chunks of 16B, XOR-swizzled: slot = chunk ^ (L&7).
// B-row PERMUTATION (R0): B staged so fragment (j,l15) = output column
// n = wn*64 + 4*l15 + j  -> epilogue j=0..3 are 4 consecutive columns.

// ---------------- GEMM1: H = relu(gather(Xb) @ W1 + b1), bf16 out ----------
__global__ __launch_bounds__(256) void gemm1_kernel(
    const unsigned short* __restrict__ xb, const unsigned short* __restrict__ w1T,
    const float* __restrict__ b1, const int* __restrict__ bidx,
    const int* __restrict__ cnt,
    unsigned short* __restrict__ H) {
    int b = blockIdx.x;
    int e = b & 7;          // XCD pin: all of expert e on XCD e
    int t2 = b >> 3;
    int nt = t2 & 7;
    int mt = t2 >> 3;
    int n_e = cnt[e];
    if (mt * 128 >= n_e) return;
    __shared__ __attribute__((aligned(16))) unsigned short As[3][64 * 64];
    __shared__ __attribute__((aligned(16))) unsigned short Bs[3][64 * 64];
    int t = threadIdx.x, wave = t >> 6, lane = t & 63;
    const int* be = bidx + e * NTOK;
    const unsigned short* agp[2]; const unsigned short* bgp[2];
    int ldsoff[2];
#pragma unroll
    for (int is = 0; is < 2; ++is) {
        int c = is * 256 + t;
        int line = c >> 3;
        int chunkg = (c & 7) ^ (line & 7);
        int sub = chunkg >> 2;
        int growl = 2 * line + sub;                       // A row (unchanged)
        int growlB = (line >> 5) * 64 + (line & 7) * 8 + sub * 4 + ((line >> 3) & 3);
        int gcol = (chunkg & 3) * 8;
        int gra = mt * 128 + growl;
        int grac = gra < n_e ? gra : n_e - 1;
        agp[is] = xb + (size_t)be[grac] * IN_DIM + gcol;
        bgp[is] = w1T + ((size_t)e * OUT_DIM + nt * 128 + growlB) * IN_DIM + gcol;
        ldsoff[is] = (is * 256 + wave * 64) * 8; // elements; lane*16B appended by HW
    }
    int wm = wave & 1, wn = wave >> 1;
    int quad = lane >> 4, l15 = lane & 15;
    int lhalf = l15 >> 1;                       // = line&7 for all frags
    int slot = (((l15 & 1) * 4 + quad) ^ lhalf) * 8; // element offset in line
    f32x4 zero4 = {0.f, 0.f, 0.f, 0.f};
    f32x4 acc[4][4];
#pragma unroll
    for (int i = 0; i < 4; ++i)
#pragma unroll
        for (int j = 0; j < 4; ++j) acc[i][j] = zero4;

    // prologue: stage k-tiles 0..1 into buffers 0..1 (8 loads/wave in flight)
#pragma unroll
    for (int pt = 0; pt < 2; ++pt)
#pragma unroll
        for (int is = 0; is < 2; ++is) {
            async16(&As[pt][ldsoff[is]], agp[is] + pt * 32);
            async16(&Bs[pt][ldsoff[is]], bgp[is] + pt * 32);
        }
    int cb = 0, sb = 2;
    for (int it = 0; it < 31; ++it) {
        asm volatile("s_waitcnt vmcnt(4)\n\ts_barrier" ::: "memory");
        if (it < 30) {
            int ktn = (it + 2) * 32;
#pragma unroll
            for (int is = 0; is < 2; ++is) {
                async16(&As[sb][ldsoff[is]], agp[is] + ktn);
                async16(&Bs[sb][ldsoff[is]], bgp[is] + ktn);
            }
        }
        kstep(As[cb], Bs[cb], acc, wm, wn, lhalf, slot);
        cb = (cb == 2) ? 0 : cb + 1;
        sb = (sb == 2) ? 0 : sb + 1;
    }
    asm volatile("s_waitcnt vmcnt(0)\n\ts_barrier" ::: "memory");
    kstep(As[cb], Bs[cb], acc, wm, wn, lhalf, slot);   // tile 31 (buf 31%3==1)

    // epilogue: + b1, relu, packed ushort4 stores (j = 4 consecutive cols)
    int hbase = prefix_cnt(cnt, e);
    const float* b1e = b1 + (size_t)e * OUT_DIM;
    int n0 = nt * 128 + wn * 64 + l15 * 4;
    float4 bias = *(const float4*)(b1e + n0);
#pragma unroll
    for (int i = 0; i < 4; ++i) {
        int m0 = mt * 128 + wm * 64 + i * 16 + quad * 4;
#pragma unroll
        for (int r = 0; r < 4; ++r) {
            int gm = m0 + r;
            if (gm < n_e) {
                float h0 = acc[i][0][r] + bias.x; h0 = h0 > 0.f ? h0 : 0.f;
                float h1 = acc[i][1][r] + bias.y; h1 = h1 > 0.f ? h1 : 0.f;
                float h2 = acc[i][2][r] + bias.z; h2 = h2 > 0.f ? h2 : 0.f;
                float h3 = acc[i][3][r] + bias.w; h3 = h3 > 0.f ? h3 : 0.f;
                ushort4 o;
                o.x = f2bf(h0); o.y = f2bf(h1); o.z = f2bf(h2); o.w = f2bf(h3);
                *(ushort4*)(H + (size_t)(hbase + gm) * OUT_DIM + n0) = o;
            }
        }
    }
}

// ---------------- GEMM2: Y = H @ W2 (packed bf16, packed stores) ------------
__global__ __launch_bounds__(256) void gemm2_kernel(
    const unsigned short* __restrict__ H, const unsigned short* __restrict__ w2T,
    const int* __restrict__ cnt,
    unsigned short* __restrict__ Y) {
    int b = blockIdx.x;
    int e = b & 7;
    int t2 = b >> 3;
    int nt = t2 & 7;
    int mt = t2 >> 3;
    int n_e = cnt[e];
    if (mt * 128 >= n_e) return;
    __shared__ __attribute__((aligned(16))) unsigned short As[3][64 * 64];
    __shared__ __attribute__((aligned(16))) unsigned short Bs[3][64 * 64];
    int t = threadIdx.x, wave = t >> 6, lane = t & 63;
    int hbase = prefix_cnt(cnt, e);
    const unsigned short* agp[2]; const unsigned short* bgp[2];
    int ldsoff[2];
#pragma unroll
    for (int is = 0; is < 2; ++is) {
        int c = is * 256 + t;
        int line = c >> 3;
        int chunkg = (c & 7) ^ (line & 7);
        int sub = chunkg >> 2;
        int growl = 2 * line + sub;
        int growlB = (line >> 5) * 64 + (line & 7) * 8 + sub * 4 + ((line >> 3) & 3);
        int gcol = (chunkg & 3) * 8;
        int gra = mt * 128 + growl;
        int grac = gra < n_e ? gra : n_e - 1;
        agp[is] = H + (size_t)(hbase + grac) * OUT_DIM + gcol;
        bgp[is] = w2T + ((size_t)e * OUT_DIM + nt * 128 + growlB) * OUT_DIM + gcol;
        ldsoff[is] = (is * 256 + wave * 64) * 8;
    }
    int wm = wave & 1, wn = wave >> 1;
    int quad = lane >> 4, l15 = lane & 15;
    int lhalf = l15 >> 1;
    int slot = (((l15 & 1) * 4 + quad) ^ lhalf) * 8;
    f32x4 zero4 = {0.f, 0.f, 0.f, 0.f};
    f32x4 acc[4][4];
#pragma unroll
    for (int i = 0; i < 4; ++i)
#pragma unroll
        for (int j = 0; j < 4; ++j) acc[i][j] = zero4;

#pragma unroll
    for (int pt = 0; pt < 2; ++pt)
#pragma unroll
        for (int is = 0; is < 2; ++is) {
            async16(&As[pt][ldsoff[is]], agp[is] + pt * 32);
            async16(&Bs[pt][ldsoff[is]], bgp[is] + pt * 32);
        }
    int cb = 0, sb = 2;
    for (int it = 0; it < 31; ++it) {
        asm volatile("s_waitcnt vmcnt(4)\n\ts_barrier" ::: "memory");
        if (it < 30) {
            int ktn = (it + 2) * 32;
#pragma unroll
            for (int is = 0; is < 2; ++is) {
                async16(&As[sb][ldsoff[is]], agp[is] + ktn);
                async16(&Bs[sb][ldsoff[is]], bgp[is] + ktn);
            }
        }
        kstep(As[cb], Bs[cb], acc, wm, wn, lhalf, slot);
        cb = (cb == 2) ? 0 : cb + 1;
        sb = (sb == 2) ? 0 : sb + 1;
    }
    asm volatile("s_waitcnt vmcnt(0)\n\ts_barrier" ::: "memory");
    kstep(As[cb], Bs[cb], acc, wm, wn, lhalf, slot);   // tile 31

    // epilogue: packed ushort4 bf16 stores to packed Y
    int n0 = nt * 128 + wn * 64 + l15 * 4;
#pragma unroll
    for (int i = 0; i < 4; ++i) {
        int m0 = mt * 128 + wm * 64 + i * 16 + quad * 4;
#pragma unroll
        for (int r = 0; r < 4; ++r) {
            int gm = m0 + r;
            if (gm < n_e) {
                ushort4 o;
                o.x = f2bf(acc[i][0][r]); o.y = f2bf(acc[i][1][r]);
                o.z = f2bf(acc[i][2][r]); o.w = f2bf(acc[i][3][r]);
                *(ushort4*)(Y + (size_t)(hbase + gm) * OUT_DIM + n0) = o;
            }
        }
    }
}

// ---------------- combine: out[tok] = g0*(Y[r0]+b2[e0]) + g1*(Y[r1]+b2[e1]) -
__global__ __launch_bounds__(256) void combine_kernel(
    const unsigned short* __restrict__ Y, const float* __restrict__ b2,
    const float2* __restrict__ gw, const int* __restrict__ slots,
    const int* __restrict__ cnt, float* __restrict__ out) {
    int t = threadIdx.x, wave = t >> 6, lane = t & 63;
    int tok = blockIdx.x * 4 + wave;
    int pre[NE];
    {
        int s = 0;
#pragma unroll
        for (int i = 0; i < NE; ++i) { pre[i] = s; s += cnt[i]; }
    }
    int s0 = slots[2 * tok], s1 = slots[2 * tok + 1];
    int e0 = s0 >> 13, e1 = s1 >> 13;
    int r0 = pre[e0] + (s0 & 8191);
    int r1 = pre[e1] + (s1 & 8191);
    float2 g = gw[tok];
    const unsigned short* y0 = Y + (size_t)r0 * OUT_DIM;
    const unsigned short* y1 = Y + (size_t)r1 * OUT_DIM;
    const float* c0 = b2 + (size_t)e0 * OUT_DIM;
    const float* c1 = b2 + (size_t)e1 * OUT_DIM;
    float* orow = out + (size_t)tok * OUT_DIM;
#pragma unroll
    for (int i = 0; i < 2; ++i) {
        int c = i * 512 + lane * 8;
        uint4 ua = *(const uint4*)(y0 + c);
        uint4 ub = *(const uint4*)(y1 + c);
        float a[8], b[8];
        bf2x(ua.x, a[0], a[1]); bf2x(ua.y, a[2], a[3]);
        bf2x(ua.z, a[4], a[5]); bf2x(ua.w, a[6], a[7]);
        bf2x(ub.x, b[0], b[1]); bf2x(ub.y, b[2], b[3]);
        bf2x(ub.z, b[4], b[5]); bf2x(ub.w, b[6], b[7]);
        float4 p0 = *(const float4*)(c0 + c);
        float4 p1 = *(const float4*)(c0 + c + 4);
        float4 q0 = *(const float4*)(c1 + c);
        float4 q1 = *(const float4*)(c1 + c + 4);
        float o[8];
        o[0] = g.x * (a[0] + p0.x) + g.y * (b[0] + q0.x);
        o[1] = g.x * (a[1] + p0.y) + g.y * (b[1] + q0.y);
        o[2] = g.x * (a[2] + p0.z) + g.y * (b[2] + q0.z);
        o[3] = g.x * (a[3] + p0.w) + g.y * (b[3] + q0.w);
        o[4] = g.x * (a[4] + p1.x) + g.y * (b[4] + q1.x);
        o[5] = g.x * (a[5] + p1.y) + g.y * (b[5] + q1.y);
        o[6] = g.x * (a[6] + p1.z) + g.y * (b[6] + q1.z);
        o[7] = g.x * (a[7] + p1.w) + g.y * (b[7] + q1.w);
        *(float4*)(orow + c) = make_float4(o[0], o[1], o[2], o[3]);
        *(float4*)(orow + c + 4) = make_float4(o[4], o[5], o[6], o[7]);
    }
}

extern "C" void kernel_launch(void* const* d_in, const int* in_sizes, int n_in,
                              void* d_out, int out_size, void* d_ws, size_t ws_size,
                              hipStream_t stream) {
    const float* x  = (const float*)d_in[0];
    const float* rw = (const float*)d_in[1];
    const float* rb = (const float*)d_in[2];
    const float* w1 = (const float*)d_in[3];
    const float* b1 = (const float*)d_in[4];
    const float* w2 = (const float*)d_in[5];
    const float* b2 = (const float*)d_in[6];
    float* out = (float*)d_out;                       // fused [8192,1024]
    float* gating = out + (size_t)NTOK * OUT_DIM;     // gating [8192,8]

    char* ws = (char*)d_ws;
    // ws layout (bytes). Y reuses [0,32MiB): xb+w1T dead after gemm1
    // (stream-ordered). enc/gw outside H region.
    unsigned short* xb  = (unsigned short*)(ws + 0);          // 16 MiB
    unsigned short* Y   = (unsigned short*)(ws + 0);          // 32 MiB (gemm2+)
    unsigned short* w1T = (unsigned short*)(ws + 16777216);   // 16 MiB
    unsigned short* w2T = (unsigned short*)(ws + 33554432);   // 16 MiB
    unsigned short* H   = (unsigned short*)(ws + 50331648);   // 32 MiB
    int*   bidx  = (int*)(ws + 83886080);                     // 256 KiB
    int*   slots = (int*)(ws + 84148224);                     // 64 KiB
    int*   cnt   = (int*)(ws + 84213760);                     // 64 B
    int*    enc  = (int*)(ws + 84213888);                     // 32 KiB
    float2* gw   = (float2*)(ws + 84246656);                  // 64 KiB

    prep_kernel<<<RBLK + 8 * 16 * 16, 256, 0, stream>>>(
        w1, w1T, x, rw, rb, xb, gating, enc, gw, cnt);
    bucket_kernel<<<NTOK / 256 + 8 * 16 * 16, 256, 0, stream>>>(
        enc, bidx, slots, cnt, w2, w2T);
    gemm1_kernel<<<8 * 8 * MT_TILES, 256, 0, stream>>>(xb, w1T, b1, bidx, cnt, H);
    gemm2_kernel<<<8 * 8 * MT_TILES, 256, 0, stream>>>(H, w2T, cnt, Y);
    combine_kernel<<<NTOK / 4, 256, 0, stream>>>(Y, b2, gw, slots, cnt, out);
    (void)in_sizes; (void)n_in; (void)out_size; (void)ws_size;
}